// Round 2
// baseline (805.653 us; speedup 1.0000x reference)
//
#include <hip/hip_runtime.h>

typedef __bf16 bf16x8 __attribute__((ext_vector_type(8)));
typedef __bf16 bf16x4 __attribute__((ext_vector_type(4)));
typedef float f32x4 __attribute__((ext_vector_type(4)));

#define MFMA_16x16x32_BF16(a, b, c) __builtin_amdgcn_mfma_f32_16x16x32_bf16(a, b, c, 0, 0, 0)

typedef const __attribute__((address_space(1))) unsigned int* gas_ptr;
typedef __attribute__((address_space(3))) unsigned int* las_ptr;

__device__ __forceinline__ void gload_lds16(const void* g, void* l) {
    __builtin_amdgcn_global_load_lds((gas_ptr)(unsigned long long)g,
                                     (las_ptr)(unsigned long long)l, 16, 0, 0);
}

// m-major ordering permutation: xm[:, b] = x[:, ORDER[b]]; out[:, ORDER[a]] = gemm_out[:, a]
__constant__ int ORDER_C[19] = {0, 2, 6, 11, 16, 3, 7, 12, 17, 1, 5, 10, 15, 8, 13, 18, 4, 9, 14};

// ---------------------------------------------------------------------------
// Kernel 1: convert all weights fp32 -> bf16 into workspace (1,048,576 elems)
// layout: fc0(409600) fc1(262144) fc2(147456) w1(16384) w2(16384) w3(196608)
// ---------------------------------------------------------------------------
__global__ __launch_bounds__(256) void wconv_kernel(
    const float* __restrict__ fc0, const float* __restrict__ fc1,
    const float* __restrict__ fc2, const float* __restrict__ rw1,
    const float* __restrict__ rw2, const float* __restrict__ rw3,
    __bf16* __restrict__ o) {
    int i4 = (blockIdx.x * 256 + threadIdx.x) * 4;
    const float* s;
    int rel;
    if (i4 < 409600)      { s = fc0; rel = i4; }
    else if (i4 < 671744) { s = fc1; rel = i4 - 409600; }
    else if (i4 < 819200) { s = fc2; rel = i4 - 671744; }
    else if (i4 < 835584) { s = rw1; rel = i4 - 819200; }
    else if (i4 < 851968) { s = rw2; rel = i4 - 835584; }
    else                  { s = rw3; rel = i4 - 851968; }
    float4 v = *(const float4*)(s + rel);
    bf16x4 b;
    b[0] = (__bf16)v.x; b[1] = (__bf16)v.y; b[2] = (__bf16)v.z; b[3] = (__bf16)v.w;
    *(bf16x4*)(o + i4) = b;
}

// ---------------------------------------------------------------------------
// Kernel 2: x_edge fp32 -> bf16 (N*128 = 4,194,304 elems; grid 4096 x 256 x 4)
// ---------------------------------------------------------------------------
__global__ __launch_bounds__(256) void xconv_kernel(const float* __restrict__ xe,
                                                    __bf16* __restrict__ o) {
    int i4 = (blockIdx.x * 256 + threadIdx.x) * 4;
    float4 v = *(const float4*)(xe + i4);
    bf16x4 b;
    b[0] = (__bf16)v.x; b[1] = (__bf16)v.y; b[2] = (__bf16)v.z; b[3] = (__bf16)v.w;
    *(bf16x4*)(o + i4) = b;
}

// ---------------------------------------------------------------------------
// Kernel 3: generic [N,128] @ W[128,128]^T -> fp32 (no bias, no epilogue).
// Tile structure cloned from radial3 (the co-validated 2x2-wave body).
// grid N/128, block 256.
// ---------------------------------------------------------------------------
__global__ __launch_bounds__(256) void gemm128_kernel(const __bf16* __restrict__ Ain,
                                                      const __bf16* __restrict__ Wb,
                                                      float* __restrict__ outp) {
    __shared__ __align__(16) __bf16 As[128 * 128];
    __shared__ __align__(16) __bf16 Bs[128 * 128];
    const int tid = threadIdx.x;
    const int w = tid >> 6, lane = tid & 63;
    const int quad = lane >> 4, l16 = lane & 15;
    const int e0 = blockIdx.x * 128;

    {
        const char* ga = (const char*)(Ain + (size_t)e0 * 128);
        const char* gb = (const char*)Wb;   // whole 128x128 weight, 32KB flat
        for (int r = 0; r < 8; ++r) {
            int boff = (r * 4 + w) * 1024 + lane * 16;
            gload_lds16(ga + boff, (char*)As + boff);
            gload_lds16(gb + boff, (char*)Bs + boff);
        }
    }
    __syncthreads();

    const int wr = w >> 1, wc = w & 1;
    f32x4 acc[4][4] = {};
    for (int ks = 0; ks < 4; ++ks) {
        bf16x8 af[4], bfr[4];
        for (int i = 0; i < 4; ++i)
            af[i] = *(const bf16x8*)&As[(wr * 64 + i * 16 + l16) * 128 + ks * 32 + quad * 8];
        for (int j = 0; j < 4; ++j)
            bfr[j] = *(const bf16x8*)&Bs[(wc * 64 + j * 16 + l16) * 128 + ks * 32 + quad * 8];
        for (int i = 0; i < 4; ++i)
            for (int j = 0; j < 4; ++j)
                acc[i][j] = MFMA_16x16x32_BF16(af[i], bfr[j], acc[i][j]);
    }

    for (int i = 0; i < 4; ++i)
        for (int j = 0; j < 4; ++j) {
            const int col = wc * 64 + j * 16 + l16;
            for (int r = 0; r < 4; ++r) {
                const int row = e0 + wr * 64 + i * 16 + quad * 4 + r;
                outp[(size_t)row * 128 + col] = acc[i][j][r];
            }
        }
}

// ---------------------------------------------------------------------------
// Kernel 4: h = silu(LN(hp + bias)) -> bf16.  One wave per row (2 cols/lane),
// full-wave shuffle reduction in fp32.  grid N/4, block 256.
// ---------------------------------------------------------------------------
__global__ __launch_bounds__(256) void lnsilu_kernel(const float* __restrict__ hp,
                                                     const float* __restrict__ bvec,
                                                     const float* __restrict__ g,
                                                     const float* __restrict__ be,
                                                     __bf16* __restrict__ hs) {
    const int tid = threadIdx.x;
    const int w = tid >> 6, lane = tid & 63;
    const int row = blockIdx.x * 4 + w;
    const float* hr = hp + (size_t)row * 128;
    float a = hr[lane] + bvec[lane];
    float b = hr[lane + 64] + bvec[lane + 64];
    float s = a + b;
    s += __shfl_xor(s, 1);  s += __shfl_xor(s, 2);  s += __shfl_xor(s, 4);
    s += __shfl_xor(s, 8);  s += __shfl_xor(s, 16); s += __shfl_xor(s, 32);
    const float mu = s * (1.f / 128.f);
    const float da = a - mu, db = b - mu;
    float v = da * da + db * db;
    v += __shfl_xor(v, 1);  v += __shfl_xor(v, 2);  v += __shfl_xor(v, 4);
    v += __shfl_xor(v, 8);  v += __shfl_xor(v, 16); v += __shfl_xor(v, 32);
    const float rs = rsqrtf(v * (1.f / 128.f) + 1e-5f);
    float ya = da * rs * g[lane] + be[lane];
    float yb = db * rs * g[lane + 64] + be[lane + 64];
    ya = ya / (1.f + __expf(-ya));
    yb = yb / (1.f + __expf(-yb));
    hs[(size_t)row * 128 + lane] = (__bf16)ya;
    hs[(size_t)row * 128 + lane + 64] = (__bf16)yb;
}

// ---------------------------------------------------------------------------
// Kernel 5: rad = h2 @ w3^T + b3 -> bf16 [N,1536].  grid (N/128, 12), 256 thr.
// ---------------------------------------------------------------------------
__global__ __launch_bounds__(256) void radial3_kernel(
    const __bf16* __restrict__ h2g, const __bf16* __restrict__ w3b,
    const float* __restrict__ b3, __bf16* __restrict__ radg) {
    __shared__ __align__(16) __bf16 As[128 * 128];
    __shared__ __align__(16) __bf16 Bs[128 * 128];
    const int tid = threadIdx.x;
    const int w = tid >> 6, lane = tid & 63;
    const int quad = lane >> 4, l16 = lane & 15;
    const int e0 = blockIdx.x * 128, n0 = blockIdx.y * 128;

    {
        const char* ga = (const char*)(h2g + (size_t)e0 * 128);
        const char* gb = (const char*)(w3b + (size_t)n0 * 128);
        for (int r = 0; r < 8; ++r) {
            int boff = (r * 4 + w) * 1024 + lane * 16;
            gload_lds16(ga + boff, (char*)As + boff);
            gload_lds16(gb + boff, (char*)Bs + boff);
        }
    }
    __syncthreads();

    const int wr = w >> 1, wc = w & 1;
    f32x4 acc[4][4] = {};
    for (int ks = 0; ks < 4; ++ks) {
        bf16x8 af[4], bfr[4];
        for (int i = 0; i < 4; ++i)
            af[i] = *(const bf16x8*)&As[(wr * 64 + i * 16 + l16) * 128 + ks * 32 + quad * 8];
        for (int j = 0; j < 4; ++j)
            bfr[j] = *(const bf16x8*)&Bs[(wc * 64 + j * 16 + l16) * 128 + ks * 32 + quad * 8];
        for (int i = 0; i < 4; ++i)
            for (int j = 0; j < 4; ++j)
                acc[i][j] = MFMA_16x16x32_BF16(af[i], bfr[j], acc[i][j]);
    }
    __syncthreads();   // all frag reads done; reuse As as output staging

    float bcol[4];
    for (int j = 0; j < 4; ++j) bcol[j] = b3[n0 + wc * 64 + j * 16 + l16];
    for (int i = 0; i < 4; ++i)
        for (int j = 0; j < 4; ++j)
            for (int r = 0; r < 4; ++r) {
                int row = wr * 64 + i * 16 + quad * 4 + r;
                int col = wc * 64 + j * 16 + l16;
                As[row * 128 + col] = (__bf16)(acc[i][j][r] + bcol[j]);
            }
    __syncthreads();
    for (int r = 0; r < 8; ++r) {
        int idx = r * 256 + tid;
        int e = idx >> 4, c = (idx & 15) * 8;
        *(uint4*)(radg + (size_t)(e0 + e) * 1536 + n0 + c) = *(const uint4*)&As[e * 128 + c];
    }
}

// ---------------------------------------------------------------------------
// Kernel 6: main fused FiLM-GEMM.  grid (N/128, 19).  blockIdx.y = one output
// coefficient row (m-major position). BK=64, tile 128x128, 4 waves (2x2).
// ---------------------------------------------------------------------------
__global__ __launch_bounds__(256) void so2_main_kernel(
    const float* __restrict__ xg, const __bf16* __restrict__ radg,
    const __bf16* __restrict__ wfc0, const __bf16* __restrict__ wfc1,
    const __bf16* __restrict__ wfc2, const float* __restrict__ fc0b,
    float* __restrict__ outg) {
    __shared__ __align__(16) __bf16 As[128 * 64];   // [edge][k]
    __shared__ __align__(16) __bf16 Bs[128 * 64];   // [outcol][k]
    const int tid = threadIdx.x;
    const int w = tid >> 6, lane = tid & 63;
    const int quad = lane >> 4, l16 = lane & 15;
    const int e0 = blockIdx.x * 128;
    const int y = blockIdx.y;

    int bstart, sz, rado, K;
    const __bf16* W;
    if (y < 5)       { bstart = 0;  sz = 5; rado = 0;    W = wfc0; K = 640; }
    else if (y < 9)  { bstart = 5;  sz = 4; rado = 640;  W = wfc1; K = 512; }
    else if (y < 13) { bstart = 9;  sz = 4; rado = 640;  W = wfc1; K = 512; }
    else if (y < 16) { bstart = 13; sz = 3; rado = 1152; W = wfc2; K = 384; }
    else             { bstart = 16; sz = 3; rado = 1152; W = wfc2; K = 384; }
    const int s_out = y - bstart;
    const int outrow = ORDER_C[y];
    const int wr = w >> 1, wc = w & 1;

    f32x4 acc[4][4] = {};

    const int e_ = tid >> 4;           // 0..15, +r*16 per staging round
    const int cA = (tid & 15) * 4;     // k within 64-wide tile, 4 elems/lane
    const char* wbase = (const char*)W + ((size_t)s_out * 128 * K) * 2;

    const int nkt = sz * 2;
    for (int kt = 0; kt < nkt; ++kt) {
        const int s_in = kt >> 1, cb = (kt & 1) * 64;
        const int xrow = ORDER_C[bstart + s_in];
        // ---- A staging: FiLM (x fp32 * rad bf16) -> bf16 LDS, perm via xrow
        {
            const float* xp = xg + (size_t)(e0 + e_) * 2432 + xrow * 128 + cb + cA;
            const __bf16* rp = radg + (size_t)(e0 + e_) * 1536 + rado + s_in * 128 + cb + cA;
            for (int r = 0; r < 8; ++r) {
                float4 xv = *(const float4*)(xp + (size_t)r * 16 * 2432);
                bf16x4 rv = *(const bf16x4*)(rp + (size_t)r * 16 * 1536);
                bf16x4 av;
                av[0] = (__bf16)(xv.x * (float)rv[0]);
                av[1] = (__bf16)(xv.y * (float)rv[1]);
                av[2] = (__bf16)(xv.z * (float)rv[2]);
                av[3] = (__bf16)(xv.w * (float)rv[3]);
                *(bf16x4*)&As[(e_ + r * 16) * 64 + cA] = av;
            }
        }
        // ---- B staging: bf16 weights, direct global->LDS 16B
        {
            const char* wkt = wbase + (size_t)kt * 128;   // kt*64 elems * 2B
            for (int r = 0; r < 4; ++r) {
                int boff = (r * 4 + w) * 1024 + lane * 16;
                int col = boff >> 7, kb = boff & 127;
                gload_lds16(wkt + (size_t)col * K * 2 + kb, (char*)Bs + boff);
            }
        }
        __syncthreads();
        for (int ks = 0; ks < 2; ++ks) {
            bf16x8 af[4], bfr[4];
            for (int i = 0; i < 4; ++i)
                af[i] = *(const bf16x8*)&As[(wr * 64 + i * 16 + l16) * 64 + ks * 32 + quad * 8];
            for (int j = 0; j < 4; ++j)
                bfr[j] = *(const bf16x8*)&Bs[(wc * 64 + j * 16 + l16) * 64 + ks * 32 + quad * 8];
            for (int i = 0; i < 4; ++i)
                for (int j = 0; j < 4; ++j)
                    acc[i][j] = MFMA_16x16x32_BF16(af[i], bfr[j], acc[i][j]);
        }
        __syncthreads();
    }

    // epilogue: bias (m0 only) + inverse-permuted store, fp32
    float bv[4];
    for (int j = 0; j < 4; ++j)
        bv[j] = (y < 5) ? fc0b[s_out * 128 + wc * 64 + j * 16 + l16] : 0.f;
    for (int i = 0; i < 4; ++i)
        for (int j = 0; j < 4; ++j) {
            const int col = wc * 64 + j * 16 + l16;
            for (int r = 0; r < 4; ++r) {
                const int row = e0 + wr * 64 + i * 16 + quad * 4 + r;
                outg[(size_t)row * 2432 + outrow * 128 + col] = acc[i][j][r] + bv[j];
            }
        }
}

// ---------------------------------------------------------------------------
extern "C" void kernel_launch(void* const* d_in, const int* in_sizes, int n_in,
                              void* d_out, int out_size, void* d_ws, size_t ws_size,
                              hipStream_t stream) {
    const float* x       = (const float*)d_in[0];
    const float* x_edge  = (const float*)d_in[1];
    const float* fc0_w   = (const float*)d_in[2];
    const float* fc0_b   = (const float*)d_in[3];
    const float* fc1_w   = (const float*)d_in[4];
    const float* fc2_w   = (const float*)d_in[5];
    const float* rad_w1  = (const float*)d_in[6];
    const float* rad_b1  = (const float*)d_in[7];
    const float* rad_g1  = (const float*)d_in[8];
    const float* rad_be1 = (const float*)d_in[9];
    const float* rad_w2  = (const float*)d_in[10];
    const float* rad_b2  = (const float*)d_in[11];
    const float* rad_g2  = (const float*)d_in[12];
    const float* rad_be2 = (const float*)d_in[13];
    const float* rad_w3  = (const float*)d_in[14];
    const float* rad_b3  = (const float*)d_in[15];
    float* out = (float*)d_out;

    const int N = in_sizes[0] / (19 * 128);   // 32768

    // workspace layout (106 MB):
    //   [0, 2MB)    wb   : bf16 weights
    //   [2, 10MB)   sh   : xeb -> h1s -> h2s (sequentially reused, 8MB)
    //   [10,106MB)  rad  : bf16 [N,1536]; first 16MB also aliases hp (fp32
    //                      pre-LN activations, dead before radial3 writes rad)
    __bf16* wb  = (__bf16*)d_ws;
    __bf16* sh  = (__bf16*)((char*)d_ws + (2u << 20));
    char*   rb  = (char*)d_ws + (10u << 20);
    float*  hp  = (float*)rb;
    __bf16* rad = (__bf16*)rb;
    __bf16* wfc0 = wb;
    __bf16* wfc1 = wb + 409600;
    __bf16* wfc2 = wb + 671744;
    __bf16* w1b  = wb + 819200;
    __bf16* w2b  = wb + 835584;
    __bf16* w3b  = wb + 851968;

    wconv_kernel<<<dim3(1024), dim3(256), 0, stream>>>(fc0_w, fc1_w, fc2_w, rad_w1, rad_w2,
                                                       rad_w3, wb);
    xconv_kernel<<<dim3(4096), dim3(256), 0, stream>>>(x_edge, sh);
    gemm128_kernel<<<dim3(N / 128), dim3(256), 0, stream>>>(sh, w1b, hp);
    lnsilu_kernel<<<dim3(N / 4), dim3(256), 0, stream>>>(hp, rad_b1, rad_g1, rad_be1, sh);
    gemm128_kernel<<<dim3(N / 128), dim3(256), 0, stream>>>(sh, w2b, hp);
    lnsilu_kernel<<<dim3(N / 4), dim3(256), 0, stream>>>(hp, rad_b2, rad_g2, rad_be2, sh);
    radial3_kernel<<<dim3(N / 128, 12), dim3(256), 0, stream>>>(sh, w3b, rad_b3, rad);
    so2_main_kernel<<<dim3(N / 128, 19), dim3(256), 0, stream>>>(x, rad, wfc0, wfc1, wfc2,
                                                                 fc0_b, out);
}